// Round 1
// baseline (2918.635 us; speedup 1.0000x reference)
//
#include <hip/hip_runtime.h>
#include <hip/hip_bf16.h>
#include <hip/hip_fp16.h>

#define S_LEN 4096
#define B_N   32
#define H_N   512
#define BH    (B_N * H_N)        // 16384
#define ROWS  32                 // s-rows per block in fused kernel
#define NCHUNK (S_LEN / ROWS)    // 128
#define CT 128                   // column tile (h_out)
#define KT 32                    // k tile (h_in)

// ---------------- K1: hsum[b,h] = sum_s hs[s,b,h] ----------------
// hs is [S][B][H] = [S][BH] with (b,h) flattened contiguous. Column sums.
__global__ __launch_bounds__(256) void hsum_kernel(const float* __restrict__ hs,
                                                   float* __restrict__ hsum) {
    int col = blockIdx.x * 256 + threadIdx.x;   // 0..BH-1
    size_t s0 = (size_t)blockIdx.y * 256;
    float acc = 0.f;
    #pragma unroll 4
    for (int i = 0; i < 256; ++i)
        acc += hs[(s0 + i) * BH + col];
    atomicAdd(&hsum[col], acc);
}

// ---------------- K2: q[b,h] = (hsum[b,:]/S) . Wq[h,:] + bq[h] ----------------
__global__ __launch_bounds__(256) void q_kernel(const float* __restrict__ hsum,
                                                const float* __restrict__ Wq,
                                                const float* __restrict__ bq,
                                                float* __restrict__ q) {
    int b = blockIdx.x, t = threadIdx.x;
    __shared__ float hrow[H_N];
    hrow[t]       = hsum[b * H_N + t]       * (1.f / S_LEN);
    hrow[t + 256] = hsum[b * H_N + t + 256] * (1.f / S_LEN);
    __syncthreads();
    for (int h = t; h < H_N; h += 256) {
        const float* wrow = Wq + (size_t)h * H_N;
        float acc = 0.f;
        #pragma unroll 8
        for (int k = 0; k < H_N; ++k) acc = fmaf(hrow[k], wrow[k], acc);
        q[b * H_N + h] = acc + bq[h];
    }
}

// ---------------- K3: fused key GEMM + tanh + scores + online softmax partials ----------------
// Block = (b, s-chunk of ROWS). Computes key tile (kept in LDS as fp16),
// scores vs q, local softmax, and partial o/m/l written to workspace.
__global__ __launch_bounds__(256) void fused_kernel(
    const float* __restrict__ hs, const float* __restrict__ Wk,
    const float* __restrict__ bk, const float* __restrict__ qv,
    const int* __restrict__ lengths,
    float* __restrict__ pm, float* __restrict__ pl, float* __restrict__ po)
{
    int blk = blockIdx.x;
    int b = blk >> 7;            // / NCHUNK (128)
    int chunk = blk & (NCHUNK - 1);
    int s0 = chunk * ROWS;
    int t = threadIdx.x;
    int ty = t >> 4;             // 0..15 -> rows 2*ty, 2*ty+1
    int tx = t & 15;             // 0..15 -> cols tx*8 .. tx*8+7 (within col tile)

    __shared__ float hs_s[KT][ROWS + 4];     // transposed [k][row], ~4.6 KiB
    __shared__ float wk_s[KT][CT + 4];       // transposed [k][col], ~16.9 KiB
    __shared__ __half key_s[ROWS][H_N];      // 32 KiB
    __shared__ float q_s[H_N];               // 2 KiB
    __shared__ float score_part[ROWS][16];   // 2 KiB
    __shared__ float score_s[ROWS];
    __shared__ float p_s[ROWS];

    q_s[t]       = qv[b * H_N + t];
    q_s[t + 256] = qv[b * H_N + t + 256];
    for (int i = t; i < ROWS * 16; i += 256) (&score_part[0][0])[i] = 0.f;

    for (int ct = 0; ct < H_N; ct += CT) {
        float acc[2][8];
        #pragma unroll
        for (int rr = 0; rr < 2; ++rr)
            #pragma unroll
            for (int cc = 0; cc < 8; ++cc) acc[rr][cc] = 0.f;

        for (int kt = 0; kt < H_N; kt += KT) {
            __syncthreads();   // protect LDS tiles from previous iteration readers
            // stage hs tile (ROWS x KT), transposed into [k][row]
            for (int i = t; i < ROWS * KT; i += 256) {
                int r = i >> 5, k = i & (KT - 1);
                hs_s[k][r] = hs[(size_t)(s0 + r) * BH + b * H_N + kt + k];
            }
            // stage Wk tile (CT x KT), transposed into [k][col]
            for (int i = t; i < CT * KT; i += 256) {
                int c = i >> 5, k = i & (KT - 1);
                wk_s[k][c] = Wk[(size_t)(ct + c) * H_N + kt + k];
            }
            __syncthreads();
            #pragma unroll
            for (int k = 0; k < KT; ++k) {
                float2 a  = *(const float2*)&hs_s[k][ty * 2];
                float4 w0 = *(const float4*)&wk_s[k][tx * 8];
                float4 w1 = *(const float4*)&wk_s[k][tx * 8 + 4];
                float wv[8] = {w0.x, w0.y, w0.z, w0.w, w1.x, w1.y, w1.z, w1.w};
                float av[2] = {a.x, a.y};
                #pragma unroll
                for (int rr = 0; rr < 2; ++rr)
                    #pragma unroll
                    for (int cc = 0; cc < 8; ++cc)
                        acc[rr][cc] = fmaf(av[rr], wv[cc], acc[rr][cc]);
            }
        }
        // epilogue for this col tile: bias + tanh + key store + score partial
        #pragma unroll
        for (int rr = 0; rr < 2; ++rr) {
            int row = ty * 2 + rr;
            float sp = 0.f;
            #pragma unroll
            for (int cc = 0; cc < 8; ++cc) {
                int c = ct + tx * 8 + cc;
                float z = acc[rr][cc] + bk[c];
                // tanh(z) = 1 - 2/(exp(2z)+1); safe at +/-inf
                float e = __expf(2.f * z);
                float kvv = 1.f - 2.f / (e + 1.f);
                key_s[row][c] = __float2half(kvv);
                sp = fmaf(kvv, q_s[c], sp);
            }
            score_part[row][tx] += sp;
        }
    }
    __syncthreads();

    // reduce scores, apply additive length mask (matches reference -10000)
    int len = lengths[b];
    if (t < ROWS) {
        float sc = 0.f;
        #pragma unroll
        for (int x = 0; x < 16; ++x) sc += score_part[t][x];
        if (s0 + t >= len) sc -= 10000.f;
        score_s[t] = sc;
    }
    __syncthreads();

    float m = -1e30f;
    #pragma unroll
    for (int r = 0; r < ROWS; ++r) m = fmaxf(m, score_s[r]);
    if (t < ROWS) p_s[t] = __expf(score_s[t] - m);
    __syncthreads();

    // partial o: each thread owns columns t and t+256
    float o0 = 0.f, o1 = 0.f;
    #pragma unroll 8
    for (int r = 0; r < ROWS; ++r) {
        float p = p_s[r];
        o0 = fmaf(p, __half2float(key_s[r][t]), o0);
        o1 = fmaf(p, __half2float(key_s[r][t + 256]), o1);
    }
    po[(size_t)blk * H_N + t]       = o0;
    po[(size_t)blk * H_N + t + 256] = o1;
    if (t == 0) {
        float l = 0.f;
        for (int r = 0; r < ROWS; ++r) l += p_s[r];
        pm[blk] = m;
        pl[blk] = l;
    }
}

// ---------------- K4: combine chunk partials ----------------
__global__ __launch_bounds__(256) void combine_kernel(
    const float* __restrict__ pm, const float* __restrict__ pl,
    const float* __restrict__ po, float* __restrict__ out)
{
    int b = blockIdx.x, t = threadIdx.x;
    float M = -1e30f;
    for (int c = 0; c < NCHUNK; ++c) M = fmaxf(M, pm[b * NCHUNK + c]);
    float den = 0.f, n0 = 0.f, n1 = 0.f;
    for (int c = 0; c < NCHUNK; ++c) {
        float w = __expf(pm[b * NCHUNK + c] - M);
        den = fmaf(w, pl[b * NCHUNK + c], den);
        const float* op = po + (size_t)(b * NCHUNK + c) * H_N;
        n0 = fmaf(w, op[t], n0);
        n1 = fmaf(w, op[t + 256], n1);
    }
    out[b * H_N + t]       = n0 / den;
    out[b * H_N + t + 256] = n1 / den;
}

extern "C" void kernel_launch(void* const* d_in, const int* in_sizes, int n_in,
                              void* d_out, int out_size, void* d_ws, size_t ws_size,
                              hipStream_t stream) {
    const float* hs      = (const float*)d_in[0];
    const float* Wq      = (const float*)d_in[1];
    const float* bq      = (const float*)d_in[2];
    const float* Wk      = (const float*)d_in[3];
    const float* bk      = (const float*)d_in[4];
    const int*   lengths = (const int*)d_in[5];
    float* out = (float*)d_out;

    float* ws   = (float*)d_ws;
    float* hsum = ws;                         // BH
    float* qv   = ws + BH;                    // BH
    float* pm   = ws + 2 * BH;                // B_N*NCHUNK = 4096
    float* pl   = pm + B_N * NCHUNK;          // 4096
    float* po   = pl + B_N * NCHUNK;          // B_N*NCHUNK*H_N = 2M floats

    hipMemsetAsync(hsum, 0, BH * sizeof(float), stream);
    hipLaunchKernelGGL(hsum_kernel, dim3(BH / 256, S_LEN / 256), dim3(256), 0, stream, hs, hsum);
    hipLaunchKernelGGL(q_kernel, dim3(B_N), dim3(256), 0, stream, hsum, Wq, bq, qv);
    hipLaunchKernelGGL(fused_kernel, dim3(B_N * NCHUNK), dim3(256), 0, stream,
                       hs, Wk, bk, qv, lengths, pm, pl, po);
    hipLaunchKernelGGL(combine_kernel, dim3(B_N), dim3(256), 0, stream, pm, pl, po, out);
}

// Round 3
// 366.157 us; speedup vs baseline: 7.9710x; 7.9710x over previous
//
#include <hip/hip_runtime.h>
#include <hip/hip_fp16.h>

#define S_LEN 4096
#define B_N   32
#define H_N   512
#define BH    (B_N * H_N)        // 16384
#define ROWS  32                 // s-rows per fused block
#define NCHUNK (S_LEN / ROWS)    // 128

typedef __attribute__((ext_vector_type(8))) short bf16x8;
typedef __attribute__((ext_vector_type(4))) float f32x4;
typedef __attribute__((ext_vector_type(4))) unsigned short us4;

__device__ __forceinline__ unsigned short f2bf(float x) {
    union { float f; unsigned u; } c; c.f = x;
    unsigned r = c.u + 0x7fffu + ((c.u >> 16) & 1u);   // RNE
    return (unsigned short)(r >> 16);
}

// ---------------- K0: Wk fp32 -> bf16 (ws), [h_out][h_in] row-major ----------------
__global__ __launch_bounds__(256) void wkconv_kernel(const float* __restrict__ Wk,
                                                     unsigned short* __restrict__ Wb) {
    size_t i = (size_t)(blockIdx.x * 256 + threadIdx.x) * 8;
    float4 v0 = *(const float4*)(Wk + i);
    float4 v1 = *(const float4*)(Wk + i + 4);
    us4 a = {f2bf(v0.x), f2bf(v0.y), f2bf(v0.z), f2bf(v0.w)};
    us4 b = {f2bf(v1.x), f2bf(v1.y), f2bf(v1.z), f2bf(v1.w)};
    *(us4*)(Wb + i)     = a;
    *(us4*)(Wb + i + 4) = b;
}

// ---------------- K1: hsum[b,h] = sum_s hs[s,b,h] (float4 columns) ----------------
__global__ __launch_bounds__(256) void hsum_kernel(const float* __restrict__ hs,
                                                   float* __restrict__ hsum) {
    int col = (blockIdx.x * 256 + threadIdx.x) * 4;      // 0..BH-1 step 4
    size_t s0 = (size_t)blockIdx.y * 256;
    float4 acc = {0.f, 0.f, 0.f, 0.f};
    #pragma unroll 4
    for (int i = 0; i < 256; ++i) {
        float4 v = *(const float4*)(hs + (s0 + i) * BH + col);
        acc.x += v.x; acc.y += v.y; acc.z += v.z; acc.w += v.w;
    }
    atomicAdd(&hsum[col],     acc.x);
    atomicAdd(&hsum[col + 1], acc.y);
    atomicAdd(&hsum[col + 2], acc.z);
    atomicAdd(&hsum[col + 3], acc.w);
}

// ---------------- K2: q[b,h] = (hsum[b,:]/S) . Wq[h,:] + bq[h] ----------------
__global__ __launch_bounds__(256) void q_kernel(const float* __restrict__ hsum,
                                                const float* __restrict__ Wq,
                                                const float* __restrict__ bq,
                                                float* __restrict__ q) {
    int b = blockIdx.x, t = threadIdx.x;
    __shared__ float hrow[H_N];
    hrow[t]       = hsum[b * H_N + t]       * (1.f / S_LEN);
    hrow[t + 256] = hsum[b * H_N + t + 256] * (1.f / S_LEN);
    __syncthreads();
    for (int h = t; h < H_N; h += 256) {
        const float* wrow = Wq + (size_t)h * H_N;
        float acc = 0.f;
        #pragma unroll 8
        for (int k = 0; k < H_N; ++k) acc = fmaf(hrow[k], wrow[k], acc);
        q[b * H_N + h] = acc + bq[h];
    }
}

// ---------------- K3: fused key GEMM (MFMA bf16) + tanh + scores + partials ----------------
// Block: 512 thr = 8 waves, one (b, 32-row chunk). Wave w owns cols w*64..w*64+63.
// A tile (32x512 bf16, XOR-swizzled byte ^= (row&7)<<4 on the intra-row offset)
// staged once in LDS; B fragments loaded straight from L2-resident bf16 Wk.
// Key tile reuses the A-tile LDS (fp16, same swizzle).
__global__ __launch_bounds__(512, 4) void fused_kernel(
    const float* __restrict__ hs, const unsigned short* __restrict__ Wb,
    const float* __restrict__ bk, const float* __restrict__ qv,
    const int* __restrict__ lengths,
    float* __restrict__ pm, float* __restrict__ pl, float* __restrict__ po)
{
    int blk = blockIdx.x;
    int b = blk >> 7;                 // / NCHUNK
    int chunk = blk & (NCHUNK - 1);
    int s0 = chunk * ROWS;
    int t = threadIdx.x;
    int lane = t & 63;
    int wv = t >> 6;                  // wave 0..7
    int l15 = lane & 15, lg = lane >> 4;   // frag row/col & k-group

    __shared__ __align__(16) unsigned short hk_s[ROWS * H_N]; // 32KB: bf16 A tile, then fp16 key tile
    __shared__ float q_s[H_N];
    __shared__ float bk_s[H_N];
    __shared__ float score_part[8][ROWS];
    __shared__ float score_s[ROWS];
    __shared__ float p_s[ROWS];

    q_s[t >= 256 ? t : t]  = 0.f;  // (no-op placeholder removed below)
    q_s[t]  = qv[b * H_N + t];     // 512 threads cover all 512 entries
    bk_s[t] = bk[t];

    // ---- stage A: hs rows -> bf16, swizzled (intra-row byte ^= (row&7)<<4) ----
    const float* hsrc = hs + (size_t)s0 * BH + (size_t)b * H_N;
    for (int i = t; i < ROWS * H_N / 4; i += 512) {      // 8 iters
        int r  = i >> 7;             // / 128 float4s per row
        int c4 = (i & 127) << 2;
        float4 v = *(const float4*)(hsrc + (size_t)r * BH + c4);
        us4 u = {f2bf(v.x), f2bf(v.y), f2bf(v.z), f2bf(v.w)};
        int byte = (c4 << 1) ^ ((r & 7) << 4);
        *(us4*)((char*)hk_s + r * 1024 + byte) = u;
    }
    __syncthreads();

    // ---- MFMA K-loop: 2 M-tiles x 4 N-tiles x 16 K-steps ----
    int n0w = wv * 64;
    int rowA0 = l15, rowA1 = 16 + l15;
    int rb0 = rowA0 * 1024, rb1 = rowA1 * 1024;
    int mA = (l15 & 7) << 4;          // same for rowA0 and rowA1
    const char* lds = (const char*)hk_s;
    const unsigned short* wb0 = Wb + (size_t)(n0w + l15) * H_N + lg * 8;

    f32x4 acc[2][4];
    #pragma unroll
    for (int m = 0; m < 2; ++m)
        #pragma unroll
        for (int n = 0; n < 4; ++n) acc[m][n] = (f32x4){0.f, 0.f, 0.f, 0.f};

    #pragma unroll 4
    for (int ks = 0; ks < 16; ++ks) {
        int off = (lg * 16 + ks * 64) ^ mA;   // XOR on full intra-row offset (no carry!)
        bf16x8 a0 = *(const bf16x8*)(lds + rb0 + off);
        bf16x8 a1 = *(const bf16x8*)(lds + rb1 + off);
        bf16x8 b0 = *(const bf16x8*)(wb0 + ks * 32);
        bf16x8 b1 = *(const bf16x8*)(wb0 + 16 * H_N + ks * 32);
        bf16x8 b2 = *(const bf16x8*)(wb0 + 32 * H_N + ks * 32);
        bf16x8 b3 = *(const bf16x8*)(wb0 + 48 * H_N + ks * 32);
        acc[0][0] = __builtin_amdgcn_mfma_f32_16x16x32_bf16(a0, b0, acc[0][0], 0, 0, 0);
        acc[1][0] = __builtin_amdgcn_mfma_f32_16x16x32_bf16(a1, b0, acc[1][0], 0, 0, 0);
        acc[0][1] = __builtin_amdgcn_mfma_f32_16x16x32_bf16(a0, b1, acc[0][1], 0, 0, 0);
        acc[1][1] = __builtin_amdgcn_mfma_f32_16x16x32_bf16(a1, b1, acc[1][1], 0, 0, 0);
        acc[0][2] = __builtin_amdgcn_mfma_f32_16x16x32_bf16(a0, b2, acc[0][2], 0, 0, 0);
        acc[1][2] = __builtin_amdgcn_mfma_f32_16x16x32_bf16(a1, b2, acc[1][2], 0, 0, 0);
        acc[0][3] = __builtin_amdgcn_mfma_f32_16x16x32_bf16(a0, b3, acc[0][3], 0, 0, 0);
        acc[1][3] = __builtin_amdgcn_mfma_f32_16x16x32_bf16(a1, b3, acc[1][3], 0, 0, 0);
    }
    __syncthreads();   // all waves done reading A tile

    // ---- epilogue: bias + tanh + key store (fp16, swizzled) + score partials ----
    // C/D layout: lane holds D[row=lg*4+i][col=l15] per 16x16 tile.
    float sp[2][4] = {{0.f,0.f,0.f,0.f},{0.f,0.f,0.f,0.f}};
    #pragma unroll
    for (int m = 0; m < 2; ++m)
        #pragma unroll
        for (int n = 0; n < 4; ++n)
            #pragma unroll
            for (int i = 0; i < 4; ++i) {
                int r = m * 16 + lg * 4 + i;
                int c = n0w + n * 16 + l15;
                float z = acc[m][n][i] + bk_s[c];
                float e = __expf(2.f * z);
                float kv = 1.f - 2.f / (e + 1.f);     // tanh(z)
                int byte = (c << 1) ^ ((r & 7) << 4);
                *(__half*)((char*)hk_s + r * 1024 + byte) = __float2half(kv);
                sp[m][i] = fmaf(kv, q_s[c], sp[m][i]);
            }
    // reduce across the 16 cols held by the l15 group, stash per-wave partial
    #pragma unroll
    for (int m = 0; m < 2; ++m)
        #pragma unroll
        for (int i = 0; i < 4; ++i) {
            float v = sp[m][i];
            v += __shfl_xor(v, 1); v += __shfl_xor(v, 2);
            v += __shfl_xor(v, 4); v += __shfl_xor(v, 8);
            if (l15 == 0) score_part[wv][m * 16 + lg * 4 + i] = v;
        }
    __syncthreads();

    // ---- softmax over the 32 rows of this chunk ----
    int len = lengths[b];
    if (t < ROWS) {
        float sc = 0.f;
        #pragma unroll
        for (int w = 0; w < 8; ++w) sc += score_part[w][t];
        if (s0 + t >= len) sc -= 10000.f;
        score_s[t] = sc;
    }
    __syncthreads();
    float mx = -1e30f;
    #pragma unroll
    for (int r = 0; r < ROWS; ++r) mx = fmaxf(mx, score_s[r]);
    if (t < ROWS) p_s[t] = __expf(score_s[t] - mx);
    __syncthreads();

    // ---- PV: o[col t] = sum_r p[r] * key[r][t] ----
    float o = 0.f;
    #pragma unroll 8
    for (int r = 0; r < ROWS; ++r) {
        int byte = (t << 1) ^ ((r & 7) << 4);
        float kv = __half2float(*(const __half*)((const char*)hk_s + r * 1024 + byte));
        o = fmaf(p_s[r], kv, o);
    }
    po[(size_t)blk * H_N + t] = o;
    if (t == 0) {
        float l = 0.f;
        for (int r = 0; r < ROWS; ++r) l += p_s[r];
        pm[blk] = mx;
        pl[blk] = l;
    }
}

// ---------------- K4: combine chunk partials ----------------
__global__ __launch_bounds__(256) void combine_kernel(
    const float* __restrict__ pm, const float* __restrict__ pl,
    const float* __restrict__ po, float* __restrict__ out)
{
    int b = blockIdx.x, t = threadIdx.x;
    float M = -1e30f;
    for (int c = 0; c < NCHUNK; ++c) M = fmaxf(M, pm[b * NCHUNK + c]);
    float den = 0.f, n0 = 0.f, n1 = 0.f;
    for (int c = 0; c < NCHUNK; ++c) {
        float w = __expf(pm[b * NCHUNK + c] - M);
        den = fmaf(w, pl[b * NCHUNK + c], den);
        const float* op = po + (size_t)(b * NCHUNK + c) * H_N;
        n0 = fmaf(w, op[t], n0);
        n1 = fmaf(w, op[t + 256], n1);
    }
    out[b * H_N + t]       = n0 / den;
    out[b * H_N + t + 256] = n1 / den;
}

extern "C" void kernel_launch(void* const* d_in, const int* in_sizes, int n_in,
                              void* d_out, int out_size, void* d_ws, size_t ws_size,
                              hipStream_t stream) {
    const float* hs      = (const float*)d_in[0];
    const float* Wq      = (const float*)d_in[1];
    const float* bq      = (const float*)d_in[2];
    const float* Wk      = (const float*)d_in[3];
    const float* bk      = (const float*)d_in[4];
    const int*   lengths = (const int*)d_in[5];
    float* out = (float*)d_out;

    float* ws   = (float*)d_ws;
    float* hsum = ws;                         // 16384
    float* qv   = ws + BH;                    // 16384
    float* pm   = ws + 2 * BH;                // 4096
    float* pl   = pm + B_N * NCHUNK;          // 4096
    float* po   = pl + B_N * NCHUNK;          // 4096*512 = 2M floats
    unsigned short* Wb = (unsigned short*)(po + (size_t)B_N * NCHUNK * H_N); // 512KB

    hipMemsetAsync(hsum, 0, BH * sizeof(float), stream);
    hipLaunchKernelGGL(wkconv_kernel, dim3(H_N * H_N / (8 * 256)), dim3(256), 0, stream, Wk, Wb);
    hipLaunchKernelGGL(hsum_kernel, dim3(BH / 1024, S_LEN / 256), dim3(256), 0, stream, hs, hsum);
    hipLaunchKernelGGL(q_kernel, dim3(B_N), dim3(256), 0, stream, hsum, Wq, bq, qv);
    hipLaunchKernelGGL(fused_kernel, dim3(B_N * NCHUNK), dim3(512), 0, stream,
                       hs, Wb, bk, qv, lengths, pm, pl, po);
    hipLaunchKernelGGL(combine_kernel, dim3(B_N), dim3(256), 0, stream, pm, pl, po, out);
}

// Round 4
// 309.783 us; speedup vs baseline: 9.4216x; 1.1820x over previous
//
#include <hip/hip_runtime.h>
#include <hip/hip_fp16.h>

#define S_LEN 4096
#define B_N   32
#define H_N   512
#define BH    (B_N * H_N)        // 16384
#define CROWS 128                // s-rows per fused block
#define NCH   (S_LEN / CROWS)    // 32 chunks per b

typedef __attribute__((ext_vector_type(8))) short bf16x8;
typedef __attribute__((ext_vector_type(4))) float f32x4;
typedef __attribute__((ext_vector_type(4))) unsigned short us4;

__device__ __forceinline__ unsigned short f2bf(float x) {
    union { float f; unsigned u; } c; c.f = x;
    unsigned r = c.u + 0x7fffu + ((c.u >> 16) & 1u);   // RNE
    return (unsigned short)(r >> 16);
}

// ---------------- K0: Wk fp32 -> bf16 ----------------
__global__ __launch_bounds__(256) void wkconv_kernel(const float* __restrict__ Wk,
                                                     unsigned short* __restrict__ Wb) {
    size_t i = (size_t)(blockIdx.x * 256 + threadIdx.x) * 8;
    float4 v0 = *(const float4*)(Wk + i);
    float4 v1 = *(const float4*)(Wk + i + 4);
    us4 a = {f2bf(v0.x), f2bf(v0.y), f2bf(v0.z), f2bf(v0.w)};
    us4 b = {f2bf(v1.x), f2bf(v1.y), f2bf(v1.z), f2bf(v1.w)};
    *(us4*)(Wb + i)     = a;
    *(us4*)(Wb + i + 4) = b;
}

// ---------------- K1: hsum[b,h] = sum_s hs[s,b,h] ----------------
__global__ __launch_bounds__(256) void hsum_kernel(const float* __restrict__ hs,
                                                   float* __restrict__ hsum) {
    int col = (blockIdx.x * 256 + threadIdx.x) * 4;
    size_t s0 = (size_t)blockIdx.y * 256;
    float4 acc = {0.f, 0.f, 0.f, 0.f};
    #pragma unroll 4
    for (int i = 0; i < 256; ++i) {
        float4 v = *(const float4*)(hs + (s0 + i) * BH + col);
        acc.x += v.x; acc.y += v.y; acc.z += v.z; acc.w += v.w;
    }
    atomicAdd(&hsum[col],     acc.x);
    atomicAdd(&hsum[col + 1], acc.y);
    atomicAdd(&hsum[col + 2], acc.z);
    atomicAdd(&hsum[col + 3], acc.w);
}

// ---------------- K2: q[b,h] ----------------
__global__ __launch_bounds__(256) void q_kernel(const float* __restrict__ hsum,
                                                const float* __restrict__ Wq,
                                                const float* __restrict__ bq,
                                                float* __restrict__ q) {
    int b = blockIdx.x, t = threadIdx.x;
    __shared__ float hrow[H_N];
    hrow[t]       = hsum[b * H_N + t]       * (1.f / S_LEN);
    hrow[t + 256] = hsum[b * H_N + t + 256] * (1.f / S_LEN);
    __syncthreads();
    for (int h = t; h < H_N; h += 256) {
        const float* wrow = Wq + (size_t)h * H_N;
        float acc = 0.f;
        #pragma unroll 8
        for (int k = 0; k < H_N; ++k) acc = fmaf(hrow[k], wrow[k], acc);
        q[b * H_N + h] = acc + bq[h];
    }
}

// ---------------- K3: fused key GEMM + tanh + scores + softmax + PV partials ----------------
// Block: 512 thr = 8 waves (2 wm x 4 wn), one (b, 128-row chunk).
// A tile 128x512 bf16 staged ONCE in LDS (swizzled), B from L2 with register
// ping-pong prefetch, key stays in acc registers (tanh in place).
__global__ __launch_bounds__(512, 2) void fused_kernel(
    const float* __restrict__ hs, const unsigned short* __restrict__ Wb,
    const float* __restrict__ bk, const float* __restrict__ qv,
    const int* __restrict__ lengths,
    float* __restrict__ pm, float* __restrict__ pl, float* __restrict__ po)
{
    int blk = blockIdx.x;
    int b = blk & 31;
    int chunk = blk >> 5;
    int s0 = chunk * CROWS;
    int t = threadIdx.x;
    int lane = t & 63, wv = t >> 6;
    int l15 = lane & 15, lg = lane >> 4;
    int wm = wv >> 2, wn = wv & 3;

    __shared__ __align__(16) unsigned short A_s[CROWS * H_N]; // 128 KB swizzled bf16
    __shared__ float q_s[H_N];
    __shared__ float bk_s[H_N];
    __shared__ float scp[4][CROWS];
    __shared__ float score_s[CROWS];
    __shared__ float p_s[CROWS];
    __shared__ float opart[8][H_N];   // 16 KB

    int len = lengths[b];
    q_s[t]  = qv[b * H_N + t];
    bk_s[t] = bk[t];

    // ---- stage A tile: 128 rows x 512 cols fp32 -> bf16, swizzle byte ^= (row&7)<<4 ----
    const float* hb = hs + ((size_t)s0 * B_N + b) * H_N;   // row stride BH floats
    int kq  = t & 127;          // quad index within row (constant per thread)
    int r0l = t >> 7;           // 0..3
    #pragma unroll 8
    for (int j = 0; j < 32; ++j) {
        int row = r0l + 4 * j;
        float4 v = *(const float4*)(hb + (size_t)row * BH + kq * 4);
        us4 u = {f2bf(v.x), f2bf(v.y), f2bf(v.z), f2bf(v.w)};
        *(us4*)((char*)A_s + row * 1024 + ((kq * 8) ^ ((row & 7) << 4))) = u;
    }
    __syncthreads();

    // ---- K-loop: 16 steps of k32, B register ping-pong prefetch ----
    const unsigned short* wbL = Wb + (size_t)(wn * 128 + l15) * H_N + lg * 8;
    const char* Ab = (const char*)A_s + (wm * 64 + l15) * 1024;
    int axor = (l15 & 7) << 4;

    f32x4 acc[4][8];
    #pragma unroll
    for (int m = 0; m < 4; ++m)
        #pragma unroll
        for (int n = 0; n < 8; ++n) acc[m][n] = (f32x4){0.f, 0.f, 0.f, 0.f};

    bf16x8 bfA[8], bfB[8];
    #pragma unroll
    for (int n = 0; n < 8; ++n) bfA[n] = *(const bf16x8*)(wbL + n * 16 * H_N);

    #pragma unroll
    for (int ks = 0; ks < 16; ks += 2) {
        // prefetch ks+1
        #pragma unroll
        for (int n = 0; n < 8; ++n)
            bfB[n] = *(const bf16x8*)(wbL + n * 16 * H_N + (ks + 1) * 32);
        {
            bf16x8 a0 = *(const bf16x8*)(Ab + 0 * 16384 + ((ks * 64 + lg * 16) ^ axor));
            bf16x8 a1 = *(const bf16x8*)(Ab + 1 * 16384 + ((ks * 64 + lg * 16) ^ axor));
            bf16x8 a2 = *(const bf16x8*)(Ab + 2 * 16384 + ((ks * 64 + lg * 16) ^ axor));
            bf16x8 a3 = *(const bf16x8*)(Ab + 3 * 16384 + ((ks * 64 + lg * 16) ^ axor));
            __builtin_amdgcn_s_setprio(1);
            #pragma unroll
            for (int n = 0; n < 8; ++n) {
                acc[0][n] = __builtin_amdgcn_mfma_f32_16x16x32_bf16(a0, bfA[n], acc[0][n], 0, 0, 0);
                acc[1][n] = __builtin_amdgcn_mfma_f32_16x16x32_bf16(a1, bfA[n], acc[1][n], 0, 0, 0);
                acc[2][n] = __builtin_amdgcn_mfma_f32_16x16x32_bf16(a2, bfA[n], acc[2][n], 0, 0, 0);
                acc[3][n] = __builtin_amdgcn_mfma_f32_16x16x32_bf16(a3, bfA[n], acc[3][n], 0, 0, 0);
            }
            __builtin_amdgcn_s_setprio(0);
        }
        // prefetch ks+2
        if (ks + 2 < 16) {
            #pragma unroll
            for (int n = 0; n < 8; ++n)
                bfA[n] = *(const bf16x8*)(wbL + n * 16 * H_N + (ks + 2) * 32);
        }
        {
            int k1 = ks + 1;
            bf16x8 a0 = *(const bf16x8*)(Ab + 0 * 16384 + ((k1 * 64 + lg * 16) ^ axor));
            bf16x8 a1 = *(const bf16x8*)(Ab + 1 * 16384 + ((k1 * 64 + lg * 16) ^ axor));
            bf16x8 a2 = *(const bf16x8*)(Ab + 2 * 16384 + ((k1 * 64 + lg * 16) ^ axor));
            bf16x8 a3 = *(const bf16x8*)(Ab + 3 * 16384 + ((k1 * 64 + lg * 16) ^ axor));
            __builtin_amdgcn_s_setprio(1);
            #pragma unroll
            for (int n = 0; n < 8; ++n) {
                acc[0][n] = __builtin_amdgcn_mfma_f32_16x16x32_bf16(a0, bfB[n], acc[0][n], 0, 0, 0);
                acc[1][n] = __builtin_amdgcn_mfma_f32_16x16x32_bf16(a1, bfB[n], acc[1][n], 0, 0, 0);
                acc[2][n] = __builtin_amdgcn_mfma_f32_16x16x32_bf16(a2, bfB[n], acc[2][n], 0, 0, 0);
                acc[3][n] = __builtin_amdgcn_mfma_f32_16x16x32_bf16(a3, bfB[n], acc[3][n], 0, 0, 0);
            }
            __builtin_amdgcn_s_setprio(0);
        }
    }

    // ---- epilogue: bias + tanh (in place) + score partials ----
    // C/D: lane holds D[row = m*16 + lg*4 + i][col = wn*128 + n*16 + l15]
    float sp[4][4] = {{0,0,0,0},{0,0,0,0},{0,0,0,0},{0,0,0,0}};
    #pragma unroll
    for (int m = 0; m < 4; ++m)
        #pragma unroll
        for (int n = 0; n < 8; ++n) {
            int c = wn * 128 + n * 16 + l15;
            float bkv = bk_s[c], qc = q_s[c];
            #pragma unroll
            for (int i = 0; i < 4; ++i) {
                float z = acc[m][n][i] + bkv;
                float e = __expf(2.f * z);
                float kv = 1.f - 2.f / (e + 1.f);     // tanh
                acc[m][n][i] = kv;                    // key kept in regs
                sp[m][i] = fmaf(kv, qc, sp[m][i]);
            }
        }
    #pragma unroll
    for (int m = 0; m < 4; ++m)
        #pragma unroll
        for (int i = 0; i < 4; ++i) {
            float v = sp[m][i];
            v += __shfl_xor(v, 1); v += __shfl_xor(v, 2);
            v += __shfl_xor(v, 4); v += __shfl_xor(v, 8);
            if (l15 == 0) scp[wn][wm * 64 + m * 16 + lg * 4 + i] = v;
        }
    __syncthreads();

    // ---- softmax over the 128 rows ----
    if (t < CROWS) {
        float sc = scp[0][t] + scp[1][t] + scp[2][t] + scp[3][t];
        if (s0 + t >= len) sc -= 10000.f;
        score_s[t] = sc;
    }
    __syncthreads();
    float mx = -1e30f;
    #pragma unroll 8
    for (int r = 0; r < CROWS; ++r) mx = fmaxf(mx, score_s[r]);
    if (t < CROWS) p_s[t] = __expf(score_s[t] - mx);
    __syncthreads();

    // ---- PV from register-resident key ----
    float o8[8] = {0,0,0,0,0,0,0,0};
    #pragma unroll
    for (int m = 0; m < 4; ++m)
        #pragma unroll
        for (int i = 0; i < 4; ++i) {
            float p = p_s[wm * 64 + m * 16 + lg * 4 + i];
            #pragma unroll
            for (int n = 0; n < 8; ++n) o8[n] = fmaf(p, acc[m][n][i], o8[n]);
        }
    int slice = wm * 4 + lg;
    #pragma unroll
    for (int n = 0; n < 8; ++n) opart[slice][wn * 128 + n * 16 + l15] = o8[n];
    __syncthreads();

    float o = 0.f;
    #pragma unroll
    for (int s = 0; s < 8; ++s) o += opart[s][t];
    po[((size_t)b * NCH + chunk) * H_N + t] = o;
    if (t == 0) {
        float l = 0.f;
        #pragma unroll 8
        for (int r = 0; r < CROWS; ++r) l += p_s[r];
        pm[b * NCH + chunk] = mx;
        pl[b * NCH + chunk] = l;
    }
}

// ---------------- K4: combine chunk partials ----------------
__global__ __launch_bounds__(256) void combine_kernel(
    const float* __restrict__ pm, const float* __restrict__ pl,
    const float* __restrict__ po, float* __restrict__ out)
{
    int b = blockIdx.x, t = threadIdx.x;
    float M = -1e30f;
    for (int c = 0; c < NCH; ++c) M = fmaxf(M, pm[b * NCH + c]);
    float den = 0.f, n0 = 0.f, n1 = 0.f;
    for (int c = 0; c < NCH; ++c) {
        float w = __expf(pm[b * NCH + c] - M);
        den = fmaf(w, pl[b * NCH + c], den);
        const float* op = po + (size_t)(b * NCH + c) * H_N;
        n0 = fmaf(w, op[t], n0);
        n1 = fmaf(w, op[t + 256], n1);
    }
    out[b * H_N + t]       = n0 / den;
    out[b * H_N + t + 256] = n1 / den;
}

extern "C" void kernel_launch(void* const* d_in, const int* in_sizes, int n_in,
                              void* d_out, int out_size, void* d_ws, size_t ws_size,
                              hipStream_t stream) {
    const float* hs      = (const float*)d_in[0];
    const float* Wq      = (const float*)d_in[1];
    const float* bq      = (const float*)d_in[2];
    const float* Wk      = (const float*)d_in[3];
    const float* bk      = (const float*)d_in[4];
    const int*   lengths = (const int*)d_in[5];
    float* out = (float*)d_out;

    float* ws   = (float*)d_ws;
    float* hsum = ws;                              // 16384
    float* qv   = hsum + BH;                       // 16384
    float* pm   = qv + BH;                         // 1024
    float* pl   = pm + B_N * NCH;                  // 1024
    float* po   = pl + B_N * NCH;                  // 32*32*512 = 524288
    unsigned short* Wb = (unsigned short*)(po + (size_t)B_N * NCH * H_N); // 512 KB

    hipMemsetAsync(hsum, 0, BH * sizeof(float), stream);
    hipLaunchKernelGGL(wkconv_kernel, dim3(H_N * H_N / (8 * 256)), dim3(256), 0, stream, Wk, Wb);
    hipLaunchKernelGGL(hsum_kernel, dim3(BH / 1024, S_LEN / 256), dim3(256), 0, stream, hs, hsum);
    hipLaunchKernelGGL(q_kernel, dim3(B_N), dim3(256), 0, stream, hsum, Wq, bq, qv);
    hipLaunchKernelGGL(fused_kernel, dim3(B_N * NCH), dim3(512), 0, stream,
                       hs, Wb, bk, qv, lengths, pm, pl, po);
    hipLaunchKernelGGL(combine_kernel, dim3(B_N), dim3(256), 0, stream, pm, pl, po, out);
}